// Round 5
// baseline (34.603 us; speedup 1.0000x reference)
//
#include <hip/hip_runtime.h>
#include <float.h>

typedef float float2v __attribute__((ext_vector_type(2)));
typedef float float4v __attribute__((ext_vector_type(4)));

// Problem constants (fixed by the reference setup_inputs()).
#define N_BATCH 4
#define P1 8192
#define P2 8192
#define D 3

#define CHUNK 128                  // targets staged in LDS per block
#define NCHUNK (P2 / CHUNK)        // 64
#define RSRC 8                     // source points per thread
#define TPB 256
#define SRC_PER_BLK (TPB * RSRC)   // 2048
#define NSRCBLK (P1 / SRC_PER_BLK) // 4
#define NMIN (N_BATCH * P1)        // 32768 per-source mins

#define TPB_R 128                  // reduce kernel block size

// Main pass: block (n, sb, c) computes, for its 2048 sources and its
// 128-target chunk, min over targets of (y^2 - 2*x.y) using packed fp32
// (v_pk_fma_f32). LDS tile is component-major (SoA) so one ds_read_b128
// of 4 consecutive x-components yields two packed operand pairs directly.
__global__ __launch_bounds__(TPB) void chamfer_main(
        const float* __restrict__ src,
        const float* __restrict__ tgt,
        float* __restrict__ ws,
        float* __restrict__ out) {
    const int bid = blockIdx.x;
    const int c   = bid % NCHUNK;
    const int sb  = (bid / NCHUNK) % NSRCBLK;
    const int n   = bid / (NCHUNK * NSRCBLK);
    const int t   = threadIdx.x;

    if (bid == 0 && t == 0) out[0] = 0.0f;

    // SoA target tile: x, y, z components scaled by -2, plus |y|^2.
    __shared__ __align__(16) float sX[CHUNK];
    __shared__ __align__(16) float sY[CHUNK];
    __shared__ __align__(16) float sZ[CHUNK];
    __shared__ __align__(16) float sW[CHUNK];

    if (t < CHUNK) {
        const int j = c * CHUNK + t;
        const float* p = tgt + ((size_t)n * P2 + j) * D;
        const float y0 = p[0], y1 = p[1], y2 = p[2];
        sX[t] = -2.0f * y0;
        sY[t] = -2.0f * y1;
        sZ[t] = -2.0f * y2;
        sW[t] = y0 * y0 + y1 * y1 + y2 * y2;
    }
    __syncthreads();

    // Per-thread sources: packed broadcast registers {x,x} for pk_fma.
    float2v bx0[RSRC], bx1[RSRC], bx2[RSRC];
    float m[RSRC];
#pragma unroll
    for (int i = 0; i < RSRC; ++i) {
        const int s = sb * SRC_PER_BLK + i * TPB + t;
        const float* p = src + ((size_t)n * P1 + s) * D;
        bx0[i] = (float2v){p[0], p[0]};
        bx1[i] = (float2v){p[1], p[1]};
        bx2[i] = (float2v){p[2], p[2]};
        m[i] = FLT_MAX;
    }

    // Groups of 8 targets: 8 clustered broadcast ds_read_b128 (SoA), then
    // 2 quad-groups x 8 sources x (2 halves x (3 pk_fma + 1 min3)) =
    // 128 VALU per group -> 2.0 VALU per source-target pair.
#pragma unroll 2
    for (int jb = 0; jb < CHUNK; jb += 8) {
        const float4v xA = *(const float4v*)&sX[jb];
        const float4v yA = *(const float4v*)&sY[jb];
        const float4v zA = *(const float4v*)&sZ[jb];
        const float4v wA = *(const float4v*)&sW[jb];
        const float4v xB = *(const float4v*)&sX[jb + 4];
        const float4v yB = *(const float4v*)&sY[jb + 4];
        const float4v zB = *(const float4v*)&sZ[jb + 4];
        const float4v wB = *(const float4v*)&sW[jb + 4];
#pragma unroll
        for (int i = 0; i < RSRC; ++i) {
            float2v d;
            d = __builtin_elementwise_fma(bx0[i], xA.xy, wA.xy);
            d = __builtin_elementwise_fma(bx1[i], yA.xy, d);
            d = __builtin_elementwise_fma(bx2[i], zA.xy, d);
            m[i] = fminf(fminf(m[i], d.x), d.y);
            d = __builtin_elementwise_fma(bx0[i], xA.zw, wA.zw);
            d = __builtin_elementwise_fma(bx1[i], yA.zw, d);
            d = __builtin_elementwise_fma(bx2[i], zA.zw, d);
            m[i] = fminf(fminf(m[i], d.x), d.y);
            d = __builtin_elementwise_fma(bx0[i], xB.xy, wB.xy);
            d = __builtin_elementwise_fma(bx1[i], yB.xy, d);
            d = __builtin_elementwise_fma(bx2[i], zB.xy, d);
            m[i] = fminf(fminf(m[i], d.x), d.y);
            d = __builtin_elementwise_fma(bx0[i], xB.zw, wB.zw);
            d = __builtin_elementwise_fma(bx1[i], yB.zw, d);
            d = __builtin_elementwise_fma(bx2[i], zB.zw, d);
            m[i] = fminf(fminf(m[i], d.x), d.y);
        }
    }

    // Race-free partial-min store (coalesced per i).
#pragma unroll
    for (int i = 0; i < RSRC; ++i) {
        const int s = n * P1 + sb * SRC_PER_BLK + i * TPB + t;
        ws[(size_t)c * NMIN + s] = m[i];
    }
}

// Reduce: per source, min over 64 chunk-partials (tree for ILP), add x^2,
// clamp, block-sum, one atomicAdd per block.
__global__ __launch_bounds__(TPB_R) void chamfer_reduce(
        const float* __restrict__ ws,
        const float* __restrict__ src,
        float* __restrict__ out) {
    const int gid = blockIdx.x * TPB_R + threadIdx.x;  // source id

    float v[NCHUNK];
#pragma unroll
    for (int c = 0; c < NCHUNK; ++c)
        v[c] = ws[(size_t)c * NMIN + gid];
#pragma unroll
    for (int s = NCHUNK / 2; s > 0; s >>= 1)
#pragma unroll
        for (int c = 0; c < s; ++c)
            v[c] = fminf(v[c], v[c + s]);

    const float* p = src + (size_t)gid * D;
    const float xs = p[0] * p[0] + p[1] * p[1] + p[2] * p[2];
    float r = fmaxf(v[0] + xs, 0.0f);

#pragma unroll
    for (int off = 32; off > 0; off >>= 1)
        r += __shfl_down(r, off, 64);
    __shared__ float sred[TPB_R / 64];
    const int lane = threadIdx.x & 63;
    const int w    = threadIdx.x >> 6;
    if (lane == 0) sred[w] = r;
    __syncthreads();
    if (threadIdx.x == 0) {
        float s = 0.0f;
#pragma unroll
        for (int i = 0; i < TPB_R / 64; ++i) s += sred[i];
        atomicAdd(out, s * (1.0f / N_BATCH));  // batch_reduction='mean'
    }
}

extern "C" void kernel_launch(void* const* d_in, const int* in_sizes, int n_in,
                              void* d_out, int out_size, void* d_ws, size_t ws_size,
                              hipStream_t stream) {
    const float* src = (const float*)d_in[0];  // (4, 8192, 3) f32
    const float* tgt = (const float*)d_in[1];  // (4, 8192, 3) f32
    float* out = (float*)d_out;                // scalar f32
    float* ws  = (float*)d_ws;                 // 64 * 32768 * 4B = 8 MB

    const int nblocks = N_BATCH * NSRCBLK * NCHUNK;  // 4*4*64 = 1024
    chamfer_main<<<nblocks, TPB, 0, stream>>>(src, tgt, ws, out);

    chamfer_reduce<<<NMIN / TPB_R, TPB_R, 0, stream>>>(ws, src, out);
}